// Round 20
// baseline (579.600 us; speedup 1.0000x reference)
//
#include <hip/hip_runtime.h>
#include <hip/hip_bf16.h>

#define DIMV 70
#define NEL 6
#define BATCH 8

typedef unsigned short u16;
typedef unsigned int u32;
typedef __bf16 bf16x8 __attribute__((ext_vector_type(8)));
typedef short short8v __attribute__((ext_vector_type(8)));
typedef float f32x4 __attribute__((ext_vector_type(4)));
typedef float f32x16 __attribute__((ext_vector_type(16)));

__device__ __forceinline__ u16 f2bf(float f) {
  __hip_bfloat16 h = __float2bfloat16(f);
  return __builtin_bit_cast(u16, h);
}
__device__ __forceinline__ float bf2f(u16 u) {
  unsigned int x = ((unsigned int)u) << 16;
  return __builtin_bit_cast(float, x);
}

// ---------------------------------------------------------------------------
// Sparse-grid scan -> per-channel atom lists (48 channels, ~34 atoms each).
__global__ __launch_bounds__(256) void k_scan(const float* __restrict__ x,
                                              int* __restrict__ cnt,
                                              int* __restrict__ lists) {
  const int N4 = (BATCH * NEL * DIMV * DIMV * DIMV) / 4;
  int i = blockIdx.x * 256 + threadIdx.x;
  if (i >= N4) return;
  float4 v = ((const float4*)x)[i];
  int ch = i / 85750;
  int local = 4 * i - ch * 343000;
  float f[4] = {v.x, v.y, v.z, v.w};
#pragma unroll
  for (int k = 0; k < 4; ++k) {
    if (f[k] != 0.f) {
      int slot = atomicAdd(&cnt[ch], 1);
      if (slot < 512) lists[ch * 512 + slot] = local + k;
    }
  }
}

// ---------------------------------------------------------------------------
// Gather-blur (plane-parallel). Writes split-packed u32 (bf16_hi<<16)|bf16_lo.
__global__ __launch_bounds__(256) void k_gather(const int* __restrict__ cnt,
                                                const int* __restrict__ lists,
                                                const float* __restrict__ sigma,
                                                u32* __restrict__ cube, int b0) {
  const int z = blockIdx.x;
  const int bl = blockIdx.y / NEL;
  const int e = blockIdx.y % NEL;
  const int chG = (b0 + bl) * NEL + e;
  const int tid = threadIdx.x;
  float sg = sigma[e];
  float inv2s2 = 1.f / (2.f * sg * sg);

  __shared__ int s_n;
  __shared__ int s_idx[512];
  __shared__ float s_wz[512];
  __shared__ float s_wy[32 * 70];
  __shared__ float s_wx[32 * 70];

  if (tid == 0) s_n = 0;
  __syncthreads();
  int n = min(cnt[chG], 512);
  for (int t = tid; t < n; t += 256) {
    int idx = lists[chG * 512 + t];
    int i0 = idx / 4900;
    float d = (float)(z - 35 - i0);
    float wz = expf(-d * d * inv2s2);
    if (wz > 1e-30f) {
      int s = atomicAdd(&s_n, 1);
      s_idx[s] = idx;
      s_wz[s] = wz;
    }
  }
  __syncthreads();
  int m = s_n;

  float acc[20];
#pragma unroll
  for (int k = 0; k < 20; ++k) acc[k] = 0.f;

  for (int t0 = 0; t0 < m; t0 += 32) {
    int tn = min(32, m - t0);
    __syncthreads();
    for (int u = tid; u < tn * 70; u += 256) {
      int t = u / 70, pos = u % 70;
      int idx = s_idx[t0 + t];
      int j0 = (idx / 70) % 70, k0 = idx % 70;
      float dy = (float)(pos - 35 - j0);
      float dx = (float)(pos - 35 - k0);
      s_wy[t * 70 + pos] = s_wz[t0 + t] * expf(-dy * dy * inv2s2);
      s_wx[t * 70 + pos] = expf(-dx * dx * inv2s2);
    }
    __syncthreads();
#pragma unroll
    for (int k = 0; k < 20; ++k) {
      int v = tid + k * 256;
      if (v < 4900) {
        int y = v / 70, xx = v % 70;
        float a = 0.f;
        for (int t = 0; t < tn; ++t)
          a = fmaf(s_wy[t * 70 + y], s_wx[t * 70 + xx], a);
        acc[k] += a;
      }
    }
  }
  size_t base = ((size_t)(bl * NEL + e) * DIMV + z) * 4900;
#pragma unroll
  for (int k = 0; k < 20; ++k) {
    int v = tid + k * 256;
    if (v < 4900) {
      float val = acc[k];
      u16 hi = f2bf(val);
      u16 lo = f2bf(val - bf2f(hi));
      cube[base + v] = ((u32)hi << 16) | (u32)lo;
    }
  }
}

// ---------------------------------------------------------------------------
// ALL weight packs + cnt zeroing in ONE kernel.
// Region 2 now packs conv2 for 32x32x16: chunk = (s*2+ch)*27+kk, c = ch*16+kc.
__device__ __forceinline__ void pack_s_one(const float* __restrict__ w,
                                           u16* __restrict__ A, int CINL,
                                           int idx) {
  int K2 = CINL * 81;
  int o = idx / K2, k = idx % K2;
  int kb = k >> 5, r = k & 31;
  int g = r >> 3, e = r & 7;
  int kk = kb % 27;
  int t = kb / 27;
  int snum = CINL >> 5;
  int sub = t % snum, s = t / snum;
  int c = sub * 32 + 8 * g + e;
  float wv = w[(o * CINL + c) * 27 + kk];
  u16 hi = f2bf(wv);
  A[idx] = (s == 2) ? f2bf(wv - bf2f(hi)) : hi;
}

__global__ __launch_bounds__(256) void k_packall(
    const float* __restrict__ w1, u16* __restrict__ Ah, u16* __restrict__ Al,
    const float* __restrict__ w2, u16* __restrict__ ap2,
    const float* __restrict__ w3, u16* __restrict__ ap3,
    const float* __restrict__ w4, u16* __restrict__ ap4,
    int* __restrict__ cnt) {
  const int R0 = 48;
  const int R1 = 32 * 224;
  const int R2 = 64 * 2592;
  const int R3 = 128 * 5184;
  const int R4 = 256 * 10368;
  int gi = blockIdx.x * 256 + threadIdx.x;
  if (gi < R0) {
    cnt[gi] = 0;
    return;
  }
  gi -= R0;
  if (gi < R1) {
    int o = gi / 224, k = gi % 224;
    int kk = k >> 5, r = k & 31;
    int g = r >> 3, e = r & 7;
    int off = 4 * kk + g;
    u16 h = 0, l = 0;
    if (off < 27 && e < 6) {
      float wv = w1[(o * 6 + e) * 27 + off];
      u16 hi = f2bf(wv);
      h = hi;
      l = f2bf(wv - bf2f(hi));
    }
    Ah[gi] = h;
    Al[gi] = l;
    return;
  }
  gi -= R1;
  if (gi < R2) {  // conv2 32x32x16 pack (r14-verified layout)
    int o = gi / 2592, k = gi % 2592;
    int chunk = k >> 4, kc = k & 15;
    int s = chunk / 54, r2 = chunk % 54;
    int ch = r2 / 27, kk2 = r2 % 27;
    int c = ch * 16 + kc;
    float wv = w2[(o * 32 + c) * 27 + kk2];
    u16 hi = f2bf(wv);
    ap2[gi] = (s == 2) ? f2bf(wv - bf2f(hi)) : hi;
    return;
  }
  gi -= R2;
  if (gi < R3) { pack_s_one(w3, ap3, 64, gi); return; }
  gi -= R3;
  if (gi < R4) { pack_s_one(w4, ap4, 128, gi); return; }
}

// ---------------------------------------------------------------------------
// conv1 + pool + ReLU (round-10 proven + setprio).
__global__ __launch_bounds__(256) void k_conv1(
    const u16* __restrict__ Ah, const u16* __restrict__ Al,
    const u32* __restrict__ cube, const float* __restrict__ bias,
    float* __restrict__ out, int b0) {
  __shared__ __align__(16) u16 Thi[1120 * 8];
  __shared__ __align__(16) u16 Tlo[1120 * 8];
  const int tid = threadIdx.x;
  const int wave = tid >> 6, lane = tid & 63;
  const int n = lane & 15, g = lane >> 4;
  const int py = blockIdx.x % 34, pz = blockIdx.x / 34;
  const int blb = blockIdx.y, bG = blb + b0;

  u32* thw = (u32*)Thi;
  u32* tlw = (u32*)Tlo;
  for (int i = tid; i < 4480; i += 256) {
    int j = i & 3, pos = i >> 2;
    int xx = pos % 70, line = pos / 70;
    int z = 2 * pz + (line >> 2), y = 2 * py + (line & 3);
    u32 a = 0, b2 = 0;
    if (j < 3) {
      size_t p0 = (((size_t)(blb * 6 + 2 * j) * 70 + z) * 70 + y) * 70 + xx;
      a = cube[p0];
      b2 = cube[p0 + 343000];
    }
    thw[pos * 4 + j] = (a >> 16) | (b2 & 0xFFFF0000u);
    tlw[pos * 4 + j] = (a & 0xFFFFu) | (b2 << 16);
  }
  __syncthreads();

  const int rc = wave;
  f32x4 acc[2][5] = {};
  for (int kk = 0; kk < 7; ++kk) {
    bf16x8 a0[2], a2[2];
#pragma unroll
    for (int mt = 0; mt < 2; ++mt) {
      a0[mt] = __builtin_bit_cast(
          bf16x8, *(const short8v*)(Ah + (size_t)(mt * 16 + n) * 224 + kk * 32 + 8 * g));
      a2[mt] = __builtin_bit_cast(
          bf16x8, *(const short8v*)(Al + (size_t)(mt * 16 + n) * 224 + kk * 32 + 8 * g));
    }
    int off = min(4 * kk + g, 26);
    int dz = off / 9, dy = (off / 3) % 3, dx = off % 3;
    int line = ((rc >> 1) + dz) * 4 + (rc & 1) + dy;
    __builtin_amdgcn_s_setprio(1);
#pragma unroll
    for (int nt = 0; nt < 5; ++nt) {
      int x_in = nt * 16 + n + dx;
      if (x_in > 69) x_in = 69;
      int cell = (line * 70 + x_in) * 8;
      bf16x8 bh = __builtin_bit_cast(bf16x8, *(const short8v*)&Thi[cell]);
      bf16x8 bl = __builtin_bit_cast(bf16x8, *(const short8v*)&Tlo[cell]);
#pragma unroll
      for (int mt = 0; mt < 2; ++mt) {
        acc[mt][nt] = __builtin_amdgcn_mfma_f32_16x16x32_bf16(a0[mt], bh, acc[mt][nt], 0, 0, 0);
        acc[mt][nt] = __builtin_amdgcn_mfma_f32_16x16x32_bf16(a2[mt], bh, acc[mt][nt], 0, 0, 0);
        acc[mt][nt] = __builtin_amdgcn_mfma_f32_16x16x32_bf16(a0[mt], bl, acc[mt][nt], 0, 0, 0);
      }
    }
    __builtin_amdgcn_s_setprio(0);
  }
  __syncthreads();
  float* Pb = (float*)Thi;  // [4][32][34]
#pragma unroll
  for (int mt = 0; mt < 2; ++mt) {
#pragma unroll
    for (int nt = 0; nt < 5; ++nt) {
#pragma unroll
      for (int r = 0; r < 4; ++r) {
        float v = acc[mt][nt][r];
        float v2 = fmaxf(v, __shfl_xor(v, 1));
        int o = mt * 16 + 4 * g + r;
        int px = (nt * 16 + n) >> 1;
        if (!(n & 1) && px < 34) Pb[(wave * 32 + o) * 34 + px] = v2;
      }
    }
  }
  __syncthreads();
  for (int t = tid; t < 1088; t += 256) {
    int o = t / 34, px = t % 34;
    float m = fmaxf(fmaxf(Pb[t], Pb[1088 + t]), fmaxf(Pb[2176 + t], Pb[3264 + t]));
    float rv = fmaxf(m + bias[o], 0.f);
    out[((((size_t)bG * 32 + o) * 34 + pz) * 34 + py) * 34 + px] = rv;
  }
}

// ---------------------------------------------------------------------------
// conv2, round-20: 32x32x16 with balanced loads. 4 waves = 2 mtiles(32 o) x
// 2 rc-pairs; N=32 lanes pack (2 rc x 16 x). Per wave per 16-K chunk:
// 2 A-loads + 2 B-ds_reads + 3 MFMA (A:B = 1:1; r14 failed at 4:1).
// Block: ds 864->432, MFMA cycles -17%, A-loads 216->432 (2x dup, tolerated).
__global__ __launch_bounds__(256) void k_conv2y(
    const u16* __restrict__ Apack, const float* __restrict__ in,
    const float* __restrict__ bias, float* __restrict__ out) {
  constexpr int DIN = 34, DP = 16, DPL = 8, XLOC = 18, COUT = 64, CINL = 32;
  __shared__ __align__(16) u16 Thi[16 * XLOC * 32];  // 18432 B
  __shared__ __align__(16) u16 Tlo[16 * XLOC * 32];

  const int tid = threadIdx.x;
  const int wave = tid >> 6, lane = tid & 63;
  const int p = lane & 31, gk = lane >> 5;
  const int m = wave >> 1, rcp = wave & 1;
  const int x = p & 15;
  const int rc = 2 * rcp + (p >> 4);
  const int xh = blockIdx.x & 1;
  const int tb = blockIdx.x >> 1;
  const int py = tb % DP, pz = tb / DP;
  const int b = blockIdx.y;

  f32x16 acc = {};

  const int E2 = 16 * XLOC * 16;
  for (int i = tid; i < E2; i += 256) {
    int xl = i % XLOC;
    int t2 = i / XLOC;
    int jp = t2 & 15;
    int line = t2 >> 4;
    int z = 2 * pz + (line >> 2), y = 2 * py + (line & 3);
    int xx = xh * 16 + xl;
    int c = 2 * jp;
    size_t base = (((size_t)(b * CINL + c) * DIN + z) * DIN + y) * DIN + xx;
    float v0 = in[base];
    float v1 = in[base + (size_t)DIN * DIN * DIN];
    u16 h0 = f2bf(v0), h1 = f2bf(v1);
    u16 l0 = f2bf(v0 - bf2f(h0));
    u16 l1 = f2bf(v1 - bf2f(h1));
    int byte = (line * XLOC + xl) * 64 + (((jp >> 2) ^ ((xl >> 1) & 3)) << 4) + ((jp & 3) << 2);
    *(u32*)((char*)Thi + byte) = (u32)h0 | ((u32)h1 << 16);
    *(u32*)((char*)Tlo + byte) = (u32)l0 | ((u32)l1 << 16);
  }
  __syncthreads();

  for (int kk = 0; kk < 27; ++kk) {
    int dz = kk / 9, dy = (kk / 3) % 3, dx = kk % 3;
    int line = ((rc >> 1) + dz) * 4 + (rc & 1) + dy;
    int xl = x + dx;  // max 15+2 = 17 = XLOC-1, no clamp
    __builtin_amdgcn_s_setprio(1);
#pragma unroll
    for (int ch = 0; ch < 2; ++ch) {
      const u16* abase = Apack + (size_t)(m * 32 + p) * 2592 + 8 * gk;
      bf16x8 a0 = __builtin_bit_cast(
          bf16x8, *(const short8v*)(abase + ((0 * 2 + ch) * 27 + kk) * 16));
      bf16x8 a2 = __builtin_bit_cast(
          bf16x8, *(const short8v*)(abase + ((2 * 2 + ch) * 27 + kk) * 16));
      int slot = (ch * 2 + gk) ^ ((xl >> 1) & 3);
      int byte = (line * XLOC + xl) * 64 + slot * 16;
      bf16x8 bh = __builtin_bit_cast(bf16x8, *(const short8v*)((const char*)Thi + byte));
      bf16x8 bl = __builtin_bit_cast(bf16x8, *(const short8v*)((const char*)Tlo + byte));
      acc = __builtin_amdgcn_mfma_f32_32x32x16_bf16(a0, bh, acc, 0, 0, 0);
      acc = __builtin_amdgcn_mfma_f32_32x32x16_bf16(a2, bh, acc, 0, 0, 0);
      acc = __builtin_amdgcn_mfma_f32_32x32x16_bf16(a0, bl, acc, 0, 0, 0);
    }
    __builtin_amdgcn_s_setprio(0);
  }
  __syncthreads();
  float* Pb = (float*)Thi;  // [4 rc][64 o][8 pxl] = 8 KB
#pragma unroll
  for (int r = 0; r < 16; ++r) {
    float v = acc[r];
    float v2 = fmaxf(v, __shfl_xor(v, 1));
    int mrow = (r & 3) + 8 * (r >> 2) + 4 * gk;
    int o = m * 32 + mrow;
    int pxl = x >> 1;
    if (!(x & 1)) Pb[(rc * COUT + o) * DPL + pxl] = v2;
  }
  __syncthreads();
  for (int t = tid; t < COUT * DPL; t += 256) {
    int o = t / DPL, pxl = t % DPL;
    float mx = fmaxf(fmaxf(Pb[t], Pb[COUT * DPL + t]),
                     fmaxf(Pb[2 * COUT * DPL + t], Pb[3 * COUT * DPL + t]));
    float rv = fmaxf(mx + bias[o], 0.f);
    int px = xh * DPL + pxl;
    out[((((size_t)b * COUT + o) * DP + pz) * DP + py) * DP + px] = rv;
  }
}

// ---------------------------------------------------------------------------
// conv3 (round-18/19 proven): merged hi/lo staging, XS=1, setprio.
template <int CINL, int COUT, int DIN, int WAVES, int XS>
__global__ __launch_bounds__(WAVES * 64) void k_conv_m(
    const u16* __restrict__ Apack, const float* __restrict__ in,
    const float* __restrict__ bias, float* __restrict__ out) {
  constexpr int DP = (DIN - 2) / 2;
  constexpr int DPL = DP / XS;
  constexpr int XLOC = (XS > 1) ? (DPL * 2 + 2) : DIN;
  constexpr int SNUM = CINL / 32;
  constexpr int K2 = 81 * CINL;
  __shared__ __align__(16) u16 Thi[16 * XLOC * 32];
  __shared__ __align__(16) u16 Tlo[16 * XLOC * 32];

  const int tid = threadIdx.x;
  const int wave = tid >> 6, lane = tid & 63;
  const int n = lane & 15, g = lane >> 4;
  const int xh = blockIdx.x % XS;
  const int tb = blockIdx.x / XS;
  const int py = tb % DP, pz = tb / DP;
  const int b = blockIdx.y;

  f32x4 acc[4][1] = {};

  for (int sub = 0; sub < SNUM; ++sub) {
    if (sub) __syncthreads();
    const int E2 = 16 * XLOC * 16;
    for (int i = tid; i < E2; i += WAVES * 64) {
      int xl = i % XLOC;
      int t2 = i / XLOC;
      int jp = t2 & 15;
      int line = t2 >> 4;
      int z = 2 * pz + (line >> 2), y = 2 * py + (line & 3);
      int xx = xh * (DPL * 2) + xl;
      int c = sub * 32 + 2 * jp;
      size_t base = (((size_t)(b * CINL + c) * DIN + z) * DIN + y) * DIN + xx;
      float v0 = in[base];
      float v1 = in[base + (size_t)DIN * DIN * DIN];
      u16 h0 = f2bf(v0), h1 = f2bf(v1);
      u16 l0 = f2bf(v0 - bf2f(h0));
      u16 l1 = f2bf(v1 - bf2f(h1));
      int byte = (line * XLOC + xl) * 64 + (((jp >> 2) ^ ((xl >> 1) & 3)) << 4) + ((jp & 3) << 2);
      *(u32*)((char*)Thi + byte) = (u32)h0 | ((u32)h1 << 16);
      *(u32*)((char*)Tlo + byte) = (u32)l0 | ((u32)l1 << 16);
    }
    __syncthreads();
    for (int kk = 0; kk < 27; ++kk) {
      const u16* abase = Apack + (size_t)(wave * 16 + n) * K2 + 8 * g;
      bf16x8 a0 = __builtin_bit_cast(
          bf16x8, *(const short8v*)(abase + ((0 * SNUM + sub) * 27 + kk) * 32));
      bf16x8 a2 = __builtin_bit_cast(
          bf16x8, *(const short8v*)(abase + ((2 * SNUM + sub) * 27 + kk) * 32));
      int dz = kk / 9, dy = (kk / 3) % 3, dx = kk % 3;
      __builtin_amdgcn_s_setprio(1);
#pragma unroll
      for (int rc = 0; rc < 4; ++rc) {
        int line = ((rc >> 1) + dz) * 4 + (rc & 1) + dy;
        int xl = n + dx;
        if (xl > XLOC - 1) xl = XLOC - 1;
        int byte = (line * XLOC + xl) * 64 + ((g ^ ((xl >> 1) & 3)) << 4);
        bf16x8 bh = __builtin_bit_cast(bf16x8, *(const short8v*)((const char*)Thi + byte));
        bf16x8 bl = __builtin_bit_cast(bf16x8, *(const short8v*)((const char*)Tlo + byte));
        acc[rc][0] = __builtin_amdgcn_mfma_f32_16x16x32_bf16(a0, bh, acc[rc][0], 0, 0, 0);
        acc[rc][0] = __builtin_amdgcn_mfma_f32_16x16x32_bf16(a2, bh, acc[rc][0], 0, 0, 0);
        acc[rc][0] = __builtin_amdgcn_mfma_f32_16x16x32_bf16(a0, bl, acc[rc][0], 0, 0, 0);
      }
      __builtin_amdgcn_s_setprio(0);
    }
  }
#pragma unroll
  for (int r = 0; r < 4; ++r) {
    float v = fmaxf(fmaxf(acc[0][0][r], acc[1][0][r]),
                    fmaxf(acc[2][0][r], acc[3][0][r]));
    float v2 = fmaxf(v, __shfl_xor(v, 1));
    int o = wave * 16 + 4 * g + r;
    int pxl = n >> 1;
    if (!(n & 1) && pxl < DPL) {
      int px = xh * DPL + pxl;
      float rv = fmaxf(v2 + bias[o], 0.f);
      out[((((size_t)b * COUT + o) * DP + pz) * DP + py) * DP + px] = rv;
    }
  }
}

// ---------------------------------------------------------------------------
// conv4, K-split + N-repacked (round-9 proven).
__global__ __launch_bounds__(512) void k_conv4ks(
    const u16* __restrict__ Apack, const float* __restrict__ in,
    float* __restrict__ P) {
  __shared__ __align__(16) u16 T[343 * 32];
  const int tid = threadIdx.x;
  const int wave = tid >> 6, lane = tid & 63;
  const int n = lane & 15, g = lane >> 4;
  const int q = blockIdx.x;
  const int third = q >> 3;
  const int r8 = q & 7;
  const int ph = r8 >> 2, sub = r8 & 3;
  const int b = blockIdx.y;

  for (int i = tid; i < 343 * 16; i += 512) {
    int jp = i & 15, pos = i >> 4;
    int c = sub * 32 + 2 * jp;
    const float* src = in + (size_t)(b * 128 + c) * 343 + pos;
    float v0 = src[0];
    float v1 = src[343];
    u16 h0 = f2bf(v0), h1 = f2bf(v1);
    u16 a0 = ph ? f2bf(v0 - bf2f(h0)) : h0;
    u16 a1 = ph ? f2bf(v1 - bf2f(h1)) : h1;
    int byte = pos * 64 + (((jp >> 2) ^ (pos & 3)) << 4) + ((jp & 3) << 2);
    *(u32*)((char*)T + byte) = (u32)a0 | ((u32)a1 << 16);
  }
  __syncthreads();

  f32x4 acc[2][4] = {};
  const int ys = n >> 2, xo = n & 3;
  for (int t = 0; t < 9; ++t) {
    int kk = third * 9 + t;
    int dz = kk / 9, dy = (kk / 3) % 3, dx = kk % 3;
    bf16x8 a0[2], a2[2];
#pragma unroll
    for (int mr = 0; mr < 2; ++mr) {
      int mtile = wave + 8 * mr;
      const u16* base = Apack + (size_t)(mtile * 16 + n) * 10368 + 8 * g;
      if (ph == 0) {
        a0[mr] = __builtin_bit_cast(
            bf16x8, *(const short8v*)(base + ((0 * 4 + sub) * 27 + kk) * 32));
        a2[mr] = __builtin_bit_cast(
            bf16x8, *(const short8v*)(base + ((2 * 4 + sub) * 27 + kk) * 32));
      } else {
        a0[mr] = __builtin_bit_cast(
            bf16x8, *(const short8v*)(base + ((1 * 4 + sub) * 27 + kk) * 32));
      }
    }
    int ybase = (ys + dy) * 7 + xo + dx;
#pragma unroll
    for (int zr = 0; zr < 4; ++zr) {
      int pos = (zr + dz) * 49 + ybase;
      int byte = pos * 64 + ((g ^ (pos & 3)) << 4);
      bf16x8 bfr = __builtin_bit_cast(bf16x8, *(const short8v*)((const char*)T + byte));
#pragma unroll
      for (int mr = 0; mr < 2; ++mr) {
        acc[mr][zr] = __builtin_amdgcn_mfma_f32_16x16x32_bf16(a0[mr], bfr, acc[mr][zr], 0, 0, 0);
        if (ph == 0)
          acc[mr][zr] = __builtin_amdgcn_mfma_f32_16x16x32_bf16(a2[mr], bfr, acc[mr][zr], 0, 0, 0);
      }
    }
  }
  float* Pq = P + (size_t)(q * 8 + b) * 16384;
#pragma unroll
  for (int mr = 0; mr < 2; ++mr) {
    int mtile = wave + 8 * mr;
#pragma unroll
    for (int zr = 0; zr < 4; ++zr) {
#pragma unroll
      for (int r = 0; r < 4; ++r) {
        int o = mtile * 16 + 4 * g + r;
        Pq[o * 64 + zr * 16 + n] = acc[mr][zr][r];
      }
    }
  }
}

__global__ __launch_bounds__(256) void k_fin4(const float* __restrict__ P,
                                              const float* __restrict__ bias,
                                              float* __restrict__ h4) {
  int t = blockIdx.x * 256 + threadIdx.x;
  if (t >= 16384) return;
  int w = t & 7;
  int o = (t >> 3) & 255;
  int b = t >> 11;
  int pd = w >> 2, p2 = (w >> 1) & 1, pw = w & 1;
  float m = -1e30f;
#pragma unroll
  for (int dz = 0; dz < 2; ++dz)
#pragma unroll
    for (int dy = 0; dy < 2; ++dy)
#pragma unroll
      for (int dx = 0; dx < 2; ++dx) {
        int pos = (2 * pd + dz) * 16 + (2 * p2 + dy) * 4 + (2 * pw + dx);
        float s = 0.f;
        for (int q = 0; q < 24; ++q)
          s += P[(size_t)(q * 8 + b) * 16384 + o * 64 + pos];
        m = fmaxf(m, s);
      }
  h4[(size_t)b * 2048 + o * 8 + w] = fmaxf(m + bias[o], 0.f);
}

// ---------------------------------------------------------------------------
// fc1 (round-15): K split 4 ways across waves, LDS cross-wave reduce.
__global__ __launch_bounds__(256) void k_fc1(const float* __restrict__ v,
                                             const float* __restrict__ W,
                                             const float* __restrict__ bias,
                                             float* __restrict__ y) {
  int o = blockIdx.x;
  int tid = threadIdx.x;
  int wave = tid >> 6, lane = tid & 63;
  __shared__ float red[4][8];
  float acc[8] = {};
  const float* wp = W + (size_t)o * 2048 + wave * 512;
  const float* vp = v + wave * 512;
  for (int k = lane; k < 512; k += 64) {
    float wv = wp[k];
#pragma unroll
    for (int bb = 0; bb < 8; ++bb)
      acc[bb] = fmaf(vp[bb * 2048 + k], wv, acc[bb]);
  }
#pragma unroll
  for (int off = 32; off; off >>= 1)
#pragma unroll
    for (int bb = 0; bb < 8; ++bb) acc[bb] += __shfl_xor(acc[bb], off);
  if (lane == 0) {
#pragma unroll
    for (int bb = 0; bb < 8; ++bb) red[wave][bb] = acc[bb];
  }
  __syncthreads();
  if (tid < 8) {
    float s = red[0][tid] + red[1][tid] + red[2][tid] + red[3][tid];
    y[tid * 1024 + o] = fmaxf(s + bias[o], 0.f);
  }
}

__global__ __launch_bounds__(64) void k_fc2(const float* __restrict__ v,
                                            const float* __restrict__ W,
                                            const float* __restrict__ bias,
                                            float* __restrict__ y) {
  int o = blockIdx.x;
  int lane = threadIdx.x;
  float acc[8] = {};
  for (int k = lane; k < 1024; k += 64) {
    float wv = W[o * 1024 + k];
#pragma unroll
    for (int bb = 0; bb < 8; ++bb)
      acc[bb] = fmaf(v[bb * 1024 + k], wv, acc[bb]);
  }
#pragma unroll
  for (int off = 32; off; off >>= 1)
#pragma unroll
    for (int bb = 0; bb < 8; ++bb) acc[bb] += __shfl_xor(acc[bb], off);
  if (lane == 0) {
    float bo = bias[o];
#pragma unroll
    for (int bb = 0; bb < 8; ++bb) y[bb * 29 + o] = acc[bb] + bo;
  }
}

// ---------------------------------------------------------------------------
extern "C" void kernel_launch(void* const* d_in, const int* in_sizes, int n_in,
                              void* d_out, int out_size, void* d_ws, size_t ws_size,
                              hipStream_t stream) {
  const float* x   = (const float*)d_in[0];
  const float* sig = (const float*)d_in[1];
  const float* w1  = (const float*)d_in[2];
  const float* b1  = (const float*)d_in[3];
  const float* w2  = (const float*)d_in[4];
  const float* b2  = (const float*)d_in[5];
  const float* w3  = (const float*)d_in[6];
  const float* b3  = (const float*)d_in[7];
  const float* w4  = (const float*)d_in[8];
  const float* b4  = (const float*)d_in[9];
  const float* fw1 = (const float*)d_in[10];
  const float* fb1 = (const float*)d_in[11];
  const float* fw2 = (const float*)d_in[12];
  const float* fb2 = (const float*)d_in[13];

  char* ws = (char*)d_ws;
  u32*   cube4 = (u32*)(ws + 0);
  float* P     = (float*)(ws + 0);
  float* h1    = (float*)(ws + 32928000);
  u16*   ah1   = (u16*)(ws + 73200000);
  u16*   al1   = (u16*)(ws + 73250000);
  u16*   ap2   = (u16*)(ws + 73300000);
  u16*   ap3   = (u16*)(ws + 73700000);
  u16*   ap4   = (u16*)(ws + 75100000);
  float* h2    = (float*)(ws + 80500000);
  float* h3    = (float*)(ws + 89000000);
  float* h4    = (float*)(ws + 90500000);
  float* y1    = (float*)(ws + 90600000);
  int*   cnt   = (int*)(ws + 90700000);
  int*   lists = (int*)(ws + 90701024);

  const int PACK_TOTAL = 48 + 32 * 224 + 64 * 2592 + 128 * 5184 + 256 * 10368;
  k_packall<<<(PACK_TOTAL + 255) / 256, 256, 0, stream>>>(
      w1, ah1, al1, w2, ap2, w3, ap3, w4, ap4, cnt);

  const int N4 = (BATCH * NEL * DIMV * DIMV * DIMV) / 4;
  k_scan<<<(N4 + 255) / 256, 256, 0, stream>>>(x, cnt, lists);

  for (int half = 0; half < 2; ++half) {
    int b0 = 4 * half;
    k_gather<<<dim3(DIMV, 4 * NEL), 256, 0, stream>>>(cnt, lists, sig, cube4, b0);
    k_conv1<<<dim3(34 * 34, 4), 256, 0, stream>>>(ah1, al1, cube4, b1, h1, b0);
  }

  k_conv2y<<<dim3(16 * 16 * 2, 8), 256, 0, stream>>>(ap2, h1, b2, h2);
  k_conv_m<64, 128, 16, 8, 1><<<dim3(7 * 7, 8), 512, 0, stream>>>(ap3, h2, b3, h3);

  k_conv4ks<<<dim3(24, 8), 512, 0, stream>>>(ap4, h3, P);
  k_fin4<<<64, 256, 0, stream>>>(P, b4, h4);

  k_fc1<<<1024, 256, 0, stream>>>(h4, fw1, fb1, y1);
  k_fc2<<<29, 64, 0, stream>>>(y1, fw2, fb2, (float*)d_out);
}

// Round 21
// 480.969 us; speedup vs baseline: 1.2051x; 1.2051x over previous
//
#include <hip/hip_runtime.h>
#include <hip/hip_bf16.h>

#define DIMV 70
#define NEL 6
#define BATCH 8

typedef unsigned short u16;
typedef unsigned int u32;
typedef __bf16 bf16x8 __attribute__((ext_vector_type(8)));
typedef short short8v __attribute__((ext_vector_type(8)));
typedef float f32x4 __attribute__((ext_vector_type(4)));

__device__ __forceinline__ u16 f2bf(float f) {
  __hip_bfloat16 h = __float2bfloat16(f);
  return __builtin_bit_cast(u16, h);
}
__device__ __forceinline__ float bf2f(u16 u) {
  unsigned int x = ((unsigned int)u) << 16;
  return __builtin_bit_cast(float, x);
}

// ---------------------------------------------------------------------------
// Sparse-grid scan -> per-channel atom lists (48 channels, ~34 atoms each).
__global__ __launch_bounds__(256) void k_scan(const float* __restrict__ x,
                                              int* __restrict__ cnt,
                                              int* __restrict__ lists) {
  const int N4 = (BATCH * NEL * DIMV * DIMV * DIMV) / 4;
  int i = blockIdx.x * 256 + threadIdx.x;
  if (i >= N4) return;
  float4 v = ((const float4*)x)[i];
  int ch = i / 85750;
  int local = 4 * i - ch * 343000;
  float f[4] = {v.x, v.y, v.z, v.w};
#pragma unroll
  for (int k = 0; k < 4; ++k) {
    if (f[k] != 0.f) {
      int slot = atomicAdd(&cnt[ch], 1);
      if (slot < 512) lists[ch * 512 + slot] = local + k;
    }
  }
}

// ---------------------------------------------------------------------------
// Gather-blur (plane-parallel). Writes split-packed u32 (bf16_hi<<16)|bf16_lo.
__global__ __launch_bounds__(256) void k_gather(const int* __restrict__ cnt,
                                                const int* __restrict__ lists,
                                                const float* __restrict__ sigma,
                                                u32* __restrict__ cube, int b0) {
  const int z = blockIdx.x;
  const int bl = blockIdx.y / NEL;
  const int e = blockIdx.y % NEL;
  const int chG = (b0 + bl) * NEL + e;
  const int tid = threadIdx.x;
  float sg = sigma[e];
  float inv2s2 = 1.f / (2.f * sg * sg);

  __shared__ int s_n;
  __shared__ int s_idx[512];
  __shared__ float s_wz[512];
  __shared__ float s_wy[32 * 70];
  __shared__ float s_wx[32 * 70];

  if (tid == 0) s_n = 0;
  __syncthreads();
  int n = min(cnt[chG], 512);
  for (int t = tid; t < n; t += 256) {
    int idx = lists[chG * 512 + t];
    int i0 = idx / 4900;
    float d = (float)(z - 35 - i0);
    float wz = expf(-d * d * inv2s2);
    if (wz > 1e-30f) {
      int s = atomicAdd(&s_n, 1);
      s_idx[s] = idx;
      s_wz[s] = wz;
    }
  }
  __syncthreads();
  int m = s_n;

  float acc[20];
#pragma unroll
  for (int k = 0; k < 20; ++k) acc[k] = 0.f;

  for (int t0 = 0; t0 < m; t0 += 32) {
    int tn = min(32, m - t0);
    __syncthreads();
    for (int u = tid; u < tn * 70; u += 256) {
      int t = u / 70, pos = u % 70;
      int idx = s_idx[t0 + t];
      int j0 = (idx / 70) % 70, k0 = idx % 70;
      float dy = (float)(pos - 35 - j0);
      float dx = (float)(pos - 35 - k0);
      s_wy[t * 70 + pos] = s_wz[t0 + t] * expf(-dy * dy * inv2s2);
      s_wx[t * 70 + pos] = expf(-dx * dx * inv2s2);
    }
    __syncthreads();
#pragma unroll
    for (int k = 0; k < 20; ++k) {
      int v = tid + k * 256;
      if (v < 4900) {
        int y = v / 70, xx = v % 70;
        float a = 0.f;
        for (int t = 0; t < tn; ++t)
          a = fmaf(s_wy[t * 70 + y], s_wx[t * 70 + xx], a);
        acc[k] += a;
      }
    }
  }
  size_t base = ((size_t)(bl * NEL + e) * DIMV + z) * 4900;
#pragma unroll
  for (int k = 0; k < 20; ++k) {
    int v = tid + k * 256;
    if (v < 4900) {
      float val = acc[k];
      u16 hi = f2bf(val);
      u16 lo = f2bf(val - bf2f(hi));
      cube[base + v] = ((u32)hi << 16) | (u32)lo;
    }
  }
}

// ---------------------------------------------------------------------------
// ALL weight packs + cnt zeroing in ONE kernel (was 5 dispatches).
__device__ __forceinline__ void pack_s_one(const float* __restrict__ w,
                                           u16* __restrict__ A, int CINL,
                                           int idx) {
  int K2 = CINL * 81;
  int o = idx / K2, k = idx % K2;
  int kb = k >> 5, r = k & 31;
  int g = r >> 3, e = r & 7;
  int kk = kb % 27;
  int t = kb / 27;
  int snum = CINL >> 5;
  int sub = t % snum, s = t / snum;
  int c = sub * 32 + 8 * g + e;
  float wv = w[(o * CINL + c) * 27 + kk];
  u16 hi = f2bf(wv);
  A[idx] = (s == 2) ? f2bf(wv - bf2f(hi)) : hi;
}

__global__ __launch_bounds__(256) void k_packall(
    const float* __restrict__ w1, u16* __restrict__ Ah, u16* __restrict__ Al,
    const float* __restrict__ w2, u16* __restrict__ ap2,
    const float* __restrict__ w3, u16* __restrict__ ap3,
    const float* __restrict__ w4, u16* __restrict__ ap4,
    int* __restrict__ cnt) {
  const int R0 = 48;
  const int R1 = 32 * 224;        // 7168
  const int R2 = 64 * 2592;       // 165888
  const int R3 = 128 * 5184;      // 663552
  const int R4 = 256 * 10368;     // 2654208
  int gi = blockIdx.x * 256 + threadIdx.x;
  if (gi < R0) {
    cnt[gi] = 0;
    return;
  }
  gi -= R0;
  if (gi < R1) {
    int o = gi / 224, k = gi % 224;
    int kk = k >> 5, r = k & 31;
    int g = r >> 3, e = r & 7;
    int off = 4 * kk + g;
    u16 h = 0, l = 0;
    if (off < 27 && e < 6) {
      float wv = w1[(o * 6 + e) * 27 + off];
      u16 hi = f2bf(wv);
      h = hi;
      l = f2bf(wv - bf2f(hi));
    }
    Ah[gi] = h;
    Al[gi] = l;
    return;
  }
  gi -= R1;
  if (gi < R2) { pack_s_one(w2, ap2, 32, gi); return; }
  gi -= R2;
  if (gi < R3) { pack_s_one(w3, ap3, 64, gi); return; }
  gi -= R3;
  if (gi < R4) { pack_s_one(w4, ap4, 128, gi); return; }
}

// ---------------------------------------------------------------------------
// conv1 + pool + ReLU (round-10 proven): wave = rc, both o-tiles per B-read.
// + s_setprio around compute cluster.
__global__ __launch_bounds__(256) void k_conv1(
    const u16* __restrict__ Ah, const u16* __restrict__ Al,
    const u32* __restrict__ cube, const float* __restrict__ bias,
    float* __restrict__ out, int b0) {
  __shared__ __align__(16) u16 Thi[1120 * 8];
  __shared__ __align__(16) u16 Tlo[1120 * 8];
  const int tid = threadIdx.x;
  const int wave = tid >> 6, lane = tid & 63;
  const int n = lane & 15, g = lane >> 4;
  const int py = blockIdx.x % 34, pz = blockIdx.x / 34;
  const int blb = blockIdx.y, bG = blb + b0;

  u32* thw = (u32*)Thi;
  u32* tlw = (u32*)Tlo;
  for (int i = tid; i < 4480; i += 256) {
    int j = i & 3, pos = i >> 2;
    int xx = pos % 70, line = pos / 70;
    int z = 2 * pz + (line >> 2), y = 2 * py + (line & 3);
    u32 a = 0, b2 = 0;
    if (j < 3) {
      size_t p0 = (((size_t)(blb * 6 + 2 * j) * 70 + z) * 70 + y) * 70 + xx;
      a = cube[p0];
      b2 = cube[p0 + 343000];
    }
    thw[pos * 4 + j] = (a >> 16) | (b2 & 0xFFFF0000u);
    tlw[pos * 4 + j] = (a & 0xFFFFu) | (b2 << 16);
  }
  __syncthreads();

  const int rc = wave;
  f32x4 acc[2][5] = {};
  for (int kk = 0; kk < 7; ++kk) {
    bf16x8 a0[2], a2[2];
#pragma unroll
    for (int mt = 0; mt < 2; ++mt) {
      a0[mt] = __builtin_bit_cast(
          bf16x8, *(const short8v*)(Ah + (size_t)(mt * 16 + n) * 224 + kk * 32 + 8 * g));
      a2[mt] = __builtin_bit_cast(
          bf16x8, *(const short8v*)(Al + (size_t)(mt * 16 + n) * 224 + kk * 32 + 8 * g));
    }
    int off = min(4 * kk + g, 26);
    int dz = off / 9, dy = (off / 3) % 3, dx = off % 3;
    int line = ((rc >> 1) + dz) * 4 + (rc & 1) + dy;
    __builtin_amdgcn_s_setprio(1);
#pragma unroll
    for (int nt = 0; nt < 5; ++nt) {
      int x_in = nt * 16 + n + dx;
      if (x_in > 69) x_in = 69;
      int cell = (line * 70 + x_in) * 8;
      bf16x8 bh = __builtin_bit_cast(bf16x8, *(const short8v*)&Thi[cell]);
      bf16x8 bl = __builtin_bit_cast(bf16x8, *(const short8v*)&Tlo[cell]);
#pragma unroll
      for (int mt = 0; mt < 2; ++mt) {
        acc[mt][nt] = __builtin_amdgcn_mfma_f32_16x16x32_bf16(a0[mt], bh, acc[mt][nt], 0, 0, 0);
        acc[mt][nt] = __builtin_amdgcn_mfma_f32_16x16x32_bf16(a2[mt], bh, acc[mt][nt], 0, 0, 0);
        acc[mt][nt] = __builtin_amdgcn_mfma_f32_16x16x32_bf16(a0[mt], bl, acc[mt][nt], 0, 0, 0);
      }
    }
    __builtin_amdgcn_s_setprio(0);
  }
  __syncthreads();
  float* Pb = (float*)Thi;  // [4][32][34]
#pragma unroll
  for (int mt = 0; mt < 2; ++mt) {
#pragma unroll
    for (int nt = 0; nt < 5; ++nt) {
#pragma unroll
      for (int r = 0; r < 4; ++r) {
        float v = acc[mt][nt][r];
        float v2 = fmaxf(v, __shfl_xor(v, 1));
        int o = mt * 16 + 4 * g + r;
        int px = (nt * 16 + n) >> 1;
        if (!(n & 1) && px < 34) Pb[(wave * 32 + o) * 34 + px] = v2;
      }
    }
  }
  __syncthreads();
  for (int t = tid; t < 1088; t += 256) {
    int o = t / 34, px = t % 34;
    float m = fmaxf(fmaxf(Pb[t], Pb[1088 + t]), fmaxf(Pb[2176 + t], Pb[3264 + t]));
    float rv = fmaxf(m + bias[o], 0.f);
    out[((((size_t)bG * 32 + o) * 34 + pz) * 34 + py) * 34 + px] = rv;
  }
}

// ---------------------------------------------------------------------------
// convs 2-3 (round-18/19 proven): merged hi/lo staging + x-split + setprio.
template <int CINL, int COUT, int DIN, int WAVES, int XS>
__global__ __launch_bounds__(WAVES * 64) void k_conv_m(
    const u16* __restrict__ Apack, const float* __restrict__ in,
    const float* __restrict__ bias, float* __restrict__ out) {
  constexpr int DP = (DIN - 2) / 2;
  constexpr int DPL = DP / XS;
  constexpr int XLOC = (XS > 1) ? (DPL * 2 + 2) : DIN;
  constexpr int SNUM = CINL / 32;
  constexpr int K2 = 81 * CINL;
  __shared__ __align__(16) u16 Thi[16 * XLOC * 32];
  __shared__ __align__(16) u16 Tlo[16 * XLOC * 32];

  const int tid = threadIdx.x;
  const int wave = tid >> 6, lane = tid & 63;
  const int n = lane & 15, g = lane >> 4;
  const int xh = blockIdx.x % XS;
  const int tb = blockIdx.x / XS;
  const int py = tb % DP, pz = tb / DP;
  const int b = blockIdx.y;

  f32x4 acc[4][1] = {};

  for (int sub = 0; sub < SNUM; ++sub) {
    if (sub) __syncthreads();
    const int E2 = 16 * XLOC * 16;
    for (int i = tid; i < E2; i += WAVES * 64) {
      int xl = i % XLOC;
      int t2 = i / XLOC;
      int jp = t2 & 15;
      int line = t2 >> 4;
      int z = 2 * pz + (line >> 2), y = 2 * py + (line & 3);
      int xx = xh * (DPL * 2) + xl;
      int c = sub * 32 + 2 * jp;
      size_t base = (((size_t)(b * CINL + c) * DIN + z) * DIN + y) * DIN + xx;
      float v0 = in[base];
      float v1 = in[base + (size_t)DIN * DIN * DIN];
      u16 h0 = f2bf(v0), h1 = f2bf(v1);
      u16 l0 = f2bf(v0 - bf2f(h0));
      u16 l1 = f2bf(v1 - bf2f(h1));
      int byte = (line * XLOC + xl) * 64 + (((jp >> 2) ^ ((xl >> 1) & 3)) << 4) + ((jp & 3) << 2);
      *(u32*)((char*)Thi + byte) = (u32)h0 | ((u32)h1 << 16);
      *(u32*)((char*)Tlo + byte) = (u32)l0 | ((u32)l1 << 16);
    }
    __syncthreads();
    for (int kk = 0; kk < 27; ++kk) {
      const u16* abase = Apack + (size_t)(wave * 16 + n) * K2 + 8 * g;
      bf16x8 a0 = __builtin_bit_cast(
          bf16x8, *(const short8v*)(abase + ((0 * SNUM + sub) * 27 + kk) * 32));
      bf16x8 a2 = __builtin_bit_cast(
          bf16x8, *(const short8v*)(abase + ((2 * SNUM + sub) * 27 + kk) * 32));
      int dz = kk / 9, dy = (kk / 3) % 3, dx = kk % 3;
      __builtin_amdgcn_s_setprio(1);
#pragma unroll
      for (int rc = 0; rc < 4; ++rc) {
        int line = ((rc >> 1) + dz) * 4 + (rc & 1) + dy;
        int xl = n + dx;
        if (xl > XLOC - 1) xl = XLOC - 1;
        int byte = (line * XLOC + xl) * 64 + ((g ^ ((xl >> 1) & 3)) << 4);
        bf16x8 bh = __builtin_bit_cast(bf16x8, *(const short8v*)((const char*)Thi + byte));
        bf16x8 bl = __builtin_bit_cast(bf16x8, *(const short8v*)((const char*)Tlo + byte));
        acc[rc][0] = __builtin_amdgcn_mfma_f32_16x16x32_bf16(a0, bh, acc[rc][0], 0, 0, 0);
        acc[rc][0] = __builtin_amdgcn_mfma_f32_16x16x32_bf16(a2, bh, acc[rc][0], 0, 0, 0);
        acc[rc][0] = __builtin_amdgcn_mfma_f32_16x16x32_bf16(a0, bl, acc[rc][0], 0, 0, 0);
      }
      __builtin_amdgcn_s_setprio(0);
    }
  }
#pragma unroll
  for (int r = 0; r < 4; ++r) {
    float v = fmaxf(fmaxf(acc[0][0][r], acc[1][0][r]),
                    fmaxf(acc[2][0][r], acc[3][0][r]));
    float v2 = fmaxf(v, __shfl_xor(v, 1));
    int o = wave * 16 + 4 * g + r;
    int pxl = n >> 1;
    if (!(n & 1) && pxl < DPL) {
      int px = xh * DPL + pxl;
      float rv = fmaxf(v2 + bias[o], 0.f);
      out[((((size_t)b * COUT + o) * DP + pz) * DP + py) * DP + px] = rv;
    }
  }
}

// ---------------------------------------------------------------------------
// conv4, K-split + N-repacked (round-9 proven).
__global__ __launch_bounds__(512) void k_conv4ks(
    const u16* __restrict__ Apack, const float* __restrict__ in,
    float* __restrict__ P) {
  __shared__ __align__(16) u16 T[343 * 32];
  const int tid = threadIdx.x;
  const int wave = tid >> 6, lane = tid & 63;
  const int n = lane & 15, g = lane >> 4;
  const int q = blockIdx.x;
  const int third = q >> 3;
  const int r8 = q & 7;
  const int ph = r8 >> 2, sub = r8 & 3;
  const int b = blockIdx.y;

  for (int i = tid; i < 343 * 16; i += 512) {
    int jp = i & 15, pos = i >> 4;
    int c = sub * 32 + 2 * jp;
    const float* src = in + (size_t)(b * 128 + c) * 343 + pos;
    float v0 = src[0];
    float v1 = src[343];
    u16 h0 = f2bf(v0), h1 = f2bf(v1);
    u16 a0 = ph ? f2bf(v0 - bf2f(h0)) : h0;
    u16 a1 = ph ? f2bf(v1 - bf2f(h1)) : h1;
    int byte = pos * 64 + (((jp >> 2) ^ (pos & 3)) << 4) + ((jp & 3) << 2);
    *(u32*)((char*)T + byte) = (u32)a0 | ((u32)a1 << 16);
  }
  __syncthreads();

  f32x4 acc[2][4] = {};
  const int ys = n >> 2, xo = n & 3;
  for (int t = 0; t < 9; ++t) {
    int kk = third * 9 + t;
    int dz = kk / 9, dy = (kk / 3) % 3, dx = kk % 3;
    bf16x8 a0[2], a2[2];
#pragma unroll
    for (int mr = 0; mr < 2; ++mr) {
      int mtile = wave + 8 * mr;
      const u16* base = Apack + (size_t)(mtile * 16 + n) * 10368 + 8 * g;
      if (ph == 0) {
        a0[mr] = __builtin_bit_cast(
            bf16x8, *(const short8v*)(base + ((0 * 4 + sub) * 27 + kk) * 32));
        a2[mr] = __builtin_bit_cast(
            bf16x8, *(const short8v*)(base + ((2 * 4 + sub) * 27 + kk) * 32));
      } else {
        a0[mr] = __builtin_bit_cast(
            bf16x8, *(const short8v*)(base + ((1 * 4 + sub) * 27 + kk) * 32));
      }
    }
    int ybase = (ys + dy) * 7 + xo + dx;
#pragma unroll
    for (int zr = 0; zr < 4; ++zr) {
      int pos = (zr + dz) * 49 + ybase;
      int byte = pos * 64 + ((g ^ (pos & 3)) << 4);
      bf16x8 bfr = __builtin_bit_cast(bf16x8, *(const short8v*)((const char*)T + byte));
#pragma unroll
      for (int mr = 0; mr < 2; ++mr) {
        acc[mr][zr] = __builtin_amdgcn_mfma_f32_16x16x32_bf16(a0[mr], bfr, acc[mr][zr], 0, 0, 0);
        if (ph == 0)
          acc[mr][zr] = __builtin_amdgcn_mfma_f32_16x16x32_bf16(a2[mr], bfr, acc[mr][zr], 0, 0, 0);
      }
    }
  }
  float* Pq = P + (size_t)(q * 8 + b) * 16384;
#pragma unroll
  for (int mr = 0; mr < 2; ++mr) {
    int mtile = wave + 8 * mr;
#pragma unroll
    for (int zr = 0; zr < 4; ++zr) {
#pragma unroll
      for (int r = 0; r < 4; ++r) {
        int o = mtile * 16 + 4 * g + r;
        Pq[o * 64 + zr * 16 + n] = acc[mr][zr][r];
      }
    }
  }
}

__global__ __launch_bounds__(256) void k_fin4(const float* __restrict__ P,
                                              const float* __restrict__ bias,
                                              float* __restrict__ h4) {
  int t = blockIdx.x * 256 + threadIdx.x;
  if (t >= 16384) return;
  int w = t & 7;
  int o = (t >> 3) & 255;
  int b = t >> 11;
  int pd = w >> 2, p2 = (w >> 1) & 1, pw = w & 1;
  float m = -1e30f;
#pragma unroll
  for (int dz = 0; dz < 2; ++dz)
#pragma unroll
    for (int dy = 0; dy < 2; ++dy)
#pragma unroll
      for (int dx = 0; dx < 2; ++dx) {
        int pos = (2 * pd + dz) * 16 + (2 * p2 + dy) * 4 + (2 * pw + dx);
        float s = 0.f;
        for (int q = 0; q < 24; ++q)
          s += P[(size_t)(q * 8 + b) * 16384 + o * 64 + pos];
        m = fmaxf(m, s);
      }
  h4[(size_t)b * 2048 + o * 8 + w] = fmaxf(m + bias[o], 0.f);
}

// ---------------------------------------------------------------------------
// fc1 (round-15): K split 4 ways across waves, LDS cross-wave reduce.
__global__ __launch_bounds__(256) void k_fc1(const float* __restrict__ v,
                                             const float* __restrict__ W,
                                             const float* __restrict__ bias,
                                             float* __restrict__ y) {
  int o = blockIdx.x;
  int tid = threadIdx.x;
  int wave = tid >> 6, lane = tid & 63;
  __shared__ float red[4][8];
  float acc[8] = {};
  const float* wp = W + (size_t)o * 2048 + wave * 512;
  const float* vp = v + wave * 512;
  for (int k = lane; k < 512; k += 64) {
    float wv = wp[k];
#pragma unroll
    for (int bb = 0; bb < 8; ++bb)
      acc[bb] = fmaf(vp[bb * 2048 + k], wv, acc[bb]);
  }
#pragma unroll
  for (int off = 32; off; off >>= 1)
#pragma unroll
    for (int bb = 0; bb < 8; ++bb) acc[bb] += __shfl_xor(acc[bb], off);
  if (lane == 0) {
#pragma unroll
    for (int bb = 0; bb < 8; ++bb) red[wave][bb] = acc[bb];
  }
  __syncthreads();
  if (tid < 8) {
    float s = red[0][tid] + red[1][tid] + red[2][tid] + red[3][tid];
    y[tid * 1024 + o] = fmaxf(s + bias[o], 0.f);
  }
}

__global__ __launch_bounds__(64) void k_fc2(const float* __restrict__ v,
                                            const float* __restrict__ W,
                                            const float* __restrict__ bias,
                                            float* __restrict__ y) {
  int o = blockIdx.x;
  int lane = threadIdx.x;
  float acc[8] = {};
  for (int k = lane; k < 1024; k += 64) {
    float wv = W[o * 1024 + k];
#pragma unroll
    for (int bb = 0; bb < 8; ++bb)
      acc[bb] = fmaf(v[bb * 1024 + k], wv, acc[bb]);
  }
#pragma unroll
  for (int off = 32; off; off >>= 1)
#pragma unroll
    for (int bb = 0; bb < 8; ++bb) acc[bb] += __shfl_xor(acc[bb], off);
  if (lane == 0) {
    float bo = bias[o];
#pragma unroll
    for (int bb = 0; bb < 8; ++bb) y[bb * 29 + o] = acc[bb] + bo;
  }
}

// ---------------------------------------------------------------------------
extern "C" void kernel_launch(void* const* d_in, const int* in_sizes, int n_in,
                              void* d_out, int out_size, void* d_ws, size_t ws_size,
                              hipStream_t stream) {
  const float* x   = (const float*)d_in[0];
  const float* sig = (const float*)d_in[1];
  const float* w1  = (const float*)d_in[2];
  const float* b1  = (const float*)d_in[3];
  const float* w2  = (const float*)d_in[4];
  const float* b2  = (const float*)d_in[5];
  const float* w3  = (const float*)d_in[6];
  const float* b3  = (const float*)d_in[7];
  const float* w4  = (const float*)d_in[8];
  const float* b4  = (const float*)d_in[9];
  const float* fw1 = (const float*)d_in[10];
  const float* fb1 = (const float*)d_in[11];
  const float* fw2 = (const float*)d_in[12];
  const float* fb2 = (const float*)d_in[13];

  char* ws = (char*)d_ws;
  u32*   cube4 = (u32*)(ws + 0);
  float* P     = (float*)(ws + 0);
  float* h1    = (float*)(ws + 32928000);
  u16*   ah1   = (u16*)(ws + 73200000);
  u16*   al1   = (u16*)(ws + 73250000);
  u16*   ap2   = (u16*)(ws + 73300000);
  u16*   ap3   = (u16*)(ws + 73700000);
  u16*   ap4   = (u16*)(ws + 75100000);
  float* h2    = (float*)(ws + 80500000);
  float* h3    = (float*)(ws + 89000000);
  float* h4    = (float*)(ws + 90500000);
  float* y1    = (float*)(ws + 90600000);
  int*   cnt   = (int*)(ws + 90700000);
  int*   lists = (int*)(ws + 90701024);

  const int PACK_TOTAL = 48 + 32 * 224 + 64 * 2592 + 128 * 5184 + 256 * 10368;
  k_packall<<<(PACK_TOTAL + 255) / 256, 256, 0, stream>>>(
      w1, ah1, al1, w2, ap2, w3, ap3, w4, ap4, cnt);

  const int N4 = (BATCH * NEL * DIMV * DIMV * DIMV) / 4;
  k_scan<<<(N4 + 255) / 256, 256, 0, stream>>>(x, cnt, lists);

  for (int half = 0; half < 2; ++half) {
    int b0 = 4 * half;
    k_gather<<<dim3(DIMV, 4 * NEL), 256, 0, stream>>>(cnt, lists, sig, cube4, b0);
    k_conv1<<<dim3(34 * 34, 4), 256, 0, stream>>>(ah1, al1, cube4, b1, h1, b0);
  }

  //          CINL COUT DIN  W  XS
  k_conv_m<32,  64, 34, 4, 2><<<dim3(16 * 16 * 2, 8), 256, 0, stream>>>(ap2, h1, b2, h2);
  k_conv_m<64, 128, 16, 8, 1><<<dim3(7 * 7, 8),       512, 0, stream>>>(ap3, h2, b3, h3);

  k_conv4ks<<<dim3(24, 8), 512, 0, stream>>>(ap4, h3, P);
  k_fin4<<<64, 256, 0, stream>>>(P, b4, h4);

  k_fc1<<<1024, 256, 0, stream>>>(h4, fw1, fb1, y1);
  k_fc2<<<29, 64, 0, stream>>>(y1, fw2, fb2, (float*)d_out);
}

// Round 22
// 458.862 us; speedup vs baseline: 1.2631x; 1.0482x over previous
//
#include <hip/hip_runtime.h>
#include <hip/hip_bf16.h>

#define DIMV 70
#define NEL 6
#define BATCH 8

typedef unsigned short u16;
typedef unsigned int u32;
typedef __bf16 bf16x8 __attribute__((ext_vector_type(8)));
typedef short short8v __attribute__((ext_vector_type(8)));
typedef float f32x4 __attribute__((ext_vector_type(4)));

__device__ __forceinline__ u16 f2bf(float f) {
  __hip_bfloat16 h = __float2bfloat16(f);
  return __builtin_bit_cast(u16, h);
}
__device__ __forceinline__ float bf2f(u16 u) {
  unsigned int x = ((unsigned int)u) << 16;
  return __builtin_bit_cast(float, x);
}

// ---------------------------------------------------------------------------
// Sparse-grid scan -> per-channel atom lists (48 channels, ~34 atoms each).
__global__ __launch_bounds__(256) void k_scan(const float* __restrict__ x,
                                              int* __restrict__ cnt,
                                              int* __restrict__ lists) {
  const int N4 = (BATCH * NEL * DIMV * DIMV * DIMV) / 4;
  int i = blockIdx.x * 256 + threadIdx.x;
  if (i >= N4) return;
  float4 v = ((const float4*)x)[i];
  int ch = i / 85750;
  int local = 4 * i - ch * 343000;
  float f[4] = {v.x, v.y, v.z, v.w};
#pragma unroll
  for (int k = 0; k < 4; ++k) {
    if (f[k] != 0.f) {
      int slot = atomicAdd(&cnt[ch], 1);
      if (slot < 512) lists[ch * 512 + slot] = local + k;
    }
  }
}

// ---------------------------------------------------------------------------
// Gather-blur (plane-parallel). Writes split-packed u32 (bf16_hi<<16)|bf16_lo.
// Works for any batch-range: bl = blockIdx.y/NEL local, b0 = global offset.
__global__ __launch_bounds__(256) void k_gather(const int* __restrict__ cnt,
                                                const int* __restrict__ lists,
                                                const float* __restrict__ sigma,
                                                u32* __restrict__ cube, int b0) {
  const int z = blockIdx.x;
  const int bl = blockIdx.y / NEL;
  const int e = blockIdx.y % NEL;
  const int chG = (b0 + bl) * NEL + e;
  const int tid = threadIdx.x;
  float sg = sigma[e];
  float inv2s2 = 1.f / (2.f * sg * sg);

  __shared__ int s_n;
  __shared__ int s_idx[512];
  __shared__ float s_wz[512];
  __shared__ float s_wy[32 * 70];
  __shared__ float s_wx[32 * 70];

  if (tid == 0) s_n = 0;
  __syncthreads();
  int n = min(cnt[chG], 512);
  for (int t = tid; t < n; t += 256) {
    int idx = lists[chG * 512 + t];
    int i0 = idx / 4900;
    float d = (float)(z - 35 - i0);
    float wz = expf(-d * d * inv2s2);
    if (wz > 1e-30f) {
      int s = atomicAdd(&s_n, 1);
      s_idx[s] = idx;
      s_wz[s] = wz;
    }
  }
  __syncthreads();
  int m = s_n;

  float acc[20];
#pragma unroll
  for (int k = 0; k < 20; ++k) acc[k] = 0.f;

  for (int t0 = 0; t0 < m; t0 += 32) {
    int tn = min(32, m - t0);
    __syncthreads();
    for (int u = tid; u < tn * 70; u += 256) {
      int t = u / 70, pos = u % 70;
      int idx = s_idx[t0 + t];
      int j0 = (idx / 70) % 70, k0 = idx % 70;
      float dy = (float)(pos - 35 - j0);
      float dx = (float)(pos - 35 - k0);
      s_wy[t * 70 + pos] = s_wz[t0 + t] * expf(-dy * dy * inv2s2);
      s_wx[t * 70 + pos] = expf(-dx * dx * inv2s2);
    }
    __syncthreads();
#pragma unroll
    for (int k = 0; k < 20; ++k) {
      int v = tid + k * 256;
      if (v < 4900) {
        int y = v / 70, xx = v % 70;
        float a = 0.f;
        for (int t = 0; t < tn; ++t)
          a = fmaf(s_wy[t * 70 + y], s_wx[t * 70 + xx], a);
        acc[k] += a;
      }
    }
  }
  size_t base = ((size_t)(bl * NEL + e) * DIMV + z) * 4900;
#pragma unroll
  for (int k = 0; k < 20; ++k) {
    int v = tid + k * 256;
    if (v < 4900) {
      float val = acc[k];
      u16 hi = f2bf(val);
      u16 lo = f2bf(val - bf2f(hi));
      cube[base + v] = ((u32)hi << 16) | (u32)lo;
    }
  }
}

// ---------------------------------------------------------------------------
// ALL weight packs + cnt zeroing in ONE kernel.
__device__ __forceinline__ void pack_s_one(const float* __restrict__ w,
                                           u16* __restrict__ A, int CINL,
                                           int idx) {
  int K2 = CINL * 81;
  int o = idx / K2, k = idx % K2;
  int kb = k >> 5, r = k & 31;
  int g = r >> 3, e = r & 7;
  int kk = kb % 27;
  int t = kb / 27;
  int snum = CINL >> 5;
  int sub = t % snum, s = t / snum;
  int c = sub * 32 + 8 * g + e;
  float wv = w[(o * CINL + c) * 27 + kk];
  u16 hi = f2bf(wv);
  A[idx] = (s == 2) ? f2bf(wv - bf2f(hi)) : hi;
}

__global__ __launch_bounds__(256) void k_packall(
    const float* __restrict__ w1, u16* __restrict__ Ah, u16* __restrict__ Al,
    const float* __restrict__ w2, u16* __restrict__ ap2,
    const float* __restrict__ w3, u16* __restrict__ ap3,
    const float* __restrict__ w4, u16* __restrict__ ap4,
    int* __restrict__ cnt) {
  const int R0 = 48;
  const int R1 = 32 * 224;
  const int R2 = 64 * 2592;
  const int R3 = 128 * 5184;
  const int R4 = 256 * 10368;
  int gi = blockIdx.x * 256 + threadIdx.x;
  if (gi < R0) {
    cnt[gi] = 0;
    return;
  }
  gi -= R0;
  if (gi < R1) {
    int o = gi / 224, k = gi % 224;
    int kk = k >> 5, r = k & 31;
    int g = r >> 3, e = r & 7;
    int off = 4 * kk + g;
    u16 h = 0, l = 0;
    if (off < 27 && e < 6) {
      float wv = w1[(o * 6 + e) * 27 + off];
      u16 hi = f2bf(wv);
      h = hi;
      l = f2bf(wv - bf2f(hi));
    }
    Ah[gi] = h;
    Al[gi] = l;
    return;
  }
  gi -= R1;
  if (gi < R2) { pack_s_one(w2, ap2, 32, gi); return; }
  gi -= R2;
  if (gi < R3) { pack_s_one(w3, ap3, 64, gi); return; }
  gi -= R3;
  if (gi < R4) { pack_s_one(w4, ap4, 128, gi); return; }
}

// ---------------------------------------------------------------------------
// conv1 + pool + ReLU (round-10 proven + setprio). Batch-range agnostic.
__global__ __launch_bounds__(256) void k_conv1(
    const u16* __restrict__ Ah, const u16* __restrict__ Al,
    const u32* __restrict__ cube, const float* __restrict__ bias,
    float* __restrict__ out, int b0) {
  __shared__ __align__(16) u16 Thi[1120 * 8];
  __shared__ __align__(16) u16 Tlo[1120 * 8];
  const int tid = threadIdx.x;
  const int wave = tid >> 6, lane = tid & 63;
  const int n = lane & 15, g = lane >> 4;
  const int py = blockIdx.x % 34, pz = blockIdx.x / 34;
  const int blb = blockIdx.y, bG = blb + b0;

  u32* thw = (u32*)Thi;
  u32* tlw = (u32*)Tlo;
  for (int i = tid; i < 4480; i += 256) {
    int j = i & 3, pos = i >> 2;
    int xx = pos % 70, line = pos / 70;
    int z = 2 * pz + (line >> 2), y = 2 * py + (line & 3);
    u32 a = 0, b2 = 0;
    if (j < 3) {
      size_t p0 = (((size_t)(blb * 6 + 2 * j) * 70 + z) * 70 + y) * 70 + xx;
      a = cube[p0];
      b2 = cube[p0 + 343000];
    }
    thw[pos * 4 + j] = (a >> 16) | (b2 & 0xFFFF0000u);
    tlw[pos * 4 + j] = (a & 0xFFFFu) | (b2 << 16);
  }
  __syncthreads();

  const int rc = wave;
  f32x4 acc[2][5] = {};
  for (int kk = 0; kk < 7; ++kk) {
    bf16x8 a0[2], a2[2];
#pragma unroll
    for (int mt = 0; mt < 2; ++mt) {
      a0[mt] = __builtin_bit_cast(
          bf16x8, *(const short8v*)(Ah + (size_t)(mt * 16 + n) * 224 + kk * 32 + 8 * g));
      a2[mt] = __builtin_bit_cast(
          bf16x8, *(const short8v*)(Al + (size_t)(mt * 16 + n) * 224 + kk * 32 + 8 * g));
    }
    int off = min(4 * kk + g, 26);
    int dz = off / 9, dy = (off / 3) % 3, dx = off % 3;
    int line = ((rc >> 1) + dz) * 4 + (rc & 1) + dy;
    __builtin_amdgcn_s_setprio(1);
#pragma unroll
    for (int nt = 0; nt < 5; ++nt) {
      int x_in = nt * 16 + n + dx;
      if (x_in > 69) x_in = 69;
      int cell = (line * 70 + x_in) * 8;
      bf16x8 bh = __builtin_bit_cast(bf16x8, *(const short8v*)&Thi[cell]);
      bf16x8 bl = __builtin_bit_cast(bf16x8, *(const short8v*)&Tlo[cell]);
#pragma unroll
      for (int mt = 0; mt < 2; ++mt) {
        acc[mt][nt] = __builtin_amdgcn_mfma_f32_16x16x32_bf16(a0[mt], bh, acc[mt][nt], 0, 0, 0);
        acc[mt][nt] = __builtin_amdgcn_mfma_f32_16x16x32_bf16(a2[mt], bh, acc[mt][nt], 0, 0, 0);
        acc[mt][nt] = __builtin_amdgcn_mfma_f32_16x16x32_bf16(a0[mt], bl, acc[mt][nt], 0, 0, 0);
      }
    }
    __builtin_amdgcn_s_setprio(0);
  }
  __syncthreads();
  float* Pb = (float*)Thi;  // [4][32][34]
#pragma unroll
  for (int mt = 0; mt < 2; ++mt) {
#pragma unroll
    for (int nt = 0; nt < 5; ++nt) {
#pragma unroll
      for (int r = 0; r < 4; ++r) {
        float v = acc[mt][nt][r];
        float v2 = fmaxf(v, __shfl_xor(v, 1));
        int o = mt * 16 + 4 * g + r;
        int px = (nt * 16 + n) >> 1;
        if (!(n & 1) && px < 34) Pb[(wave * 32 + o) * 34 + px] = v2;
      }
    }
  }
  __syncthreads();
  for (int t = tid; t < 1088; t += 256) {
    int o = t / 34, px = t % 34;
    float m = fmaxf(fmaxf(Pb[t], Pb[1088 + t]), fmaxf(Pb[2176 + t], Pb[3264 + t]));
    float rv = fmaxf(m + bias[o], 0.f);
    out[((((size_t)bG * 32 + o) * 34 + pz) * 34 + py) * 34 + px] = rv;
  }
}

// ---------------------------------------------------------------------------
// convs 2-3 (round-18/19 proven): merged hi/lo staging + x-split + setprio.
template <int CINL, int COUT, int DIN, int WAVES, int XS>
__global__ __launch_bounds__(WAVES * 64) void k_conv_m(
    const u16* __restrict__ Apack, const float* __restrict__ in,
    const float* __restrict__ bias, float* __restrict__ out) {
  constexpr int DP = (DIN - 2) / 2;
  constexpr int DPL = DP / XS;
  constexpr int XLOC = (XS > 1) ? (DPL * 2 + 2) : DIN;
  constexpr int SNUM = CINL / 32;
  constexpr int K2 = 81 * CINL;
  __shared__ __align__(16) u16 Thi[16 * XLOC * 32];
  __shared__ __align__(16) u16 Tlo[16 * XLOC * 32];

  const int tid = threadIdx.x;
  const int wave = tid >> 6, lane = tid & 63;
  const int n = lane & 15, g = lane >> 4;
  const int xh = blockIdx.x % XS;
  const int tb = blockIdx.x / XS;
  const int py = tb % DP, pz = tb / DP;
  const int b = blockIdx.y;

  f32x4 acc[4][1] = {};

  for (int sub = 0; sub < SNUM; ++sub) {
    if (sub) __syncthreads();
    const int E2 = 16 * XLOC * 16;
    for (int i = tid; i < E2; i += WAVES * 64) {
      int xl = i % XLOC;
      int t2 = i / XLOC;
      int jp = t2 & 15;
      int line = t2 >> 4;
      int z = 2 * pz + (line >> 2), y = 2 * py + (line & 3);
      int xx = xh * (DPL * 2) + xl;
      int c = sub * 32 + 2 * jp;
      size_t base = (((size_t)(b * CINL + c) * DIN + z) * DIN + y) * DIN + xx;
      float v0 = in[base];
      float v1 = in[base + (size_t)DIN * DIN * DIN];
      u16 h0 = f2bf(v0), h1 = f2bf(v1);
      u16 l0 = f2bf(v0 - bf2f(h0));
      u16 l1 = f2bf(v1 - bf2f(h1));
      int byte = (line * XLOC + xl) * 64 + (((jp >> 2) ^ ((xl >> 1) & 3)) << 4) + ((jp & 3) << 2);
      *(u32*)((char*)Thi + byte) = (u32)h0 | ((u32)h1 << 16);
      *(u32*)((char*)Tlo + byte) = (u32)l0 | ((u32)l1 << 16);
    }
    __syncthreads();
    for (int kk = 0; kk < 27; ++kk) {
      const u16* abase = Apack + (size_t)(wave * 16 + n) * K2 + 8 * g;
      bf16x8 a0 = __builtin_bit_cast(
          bf16x8, *(const short8v*)(abase + ((0 * SNUM + sub) * 27 + kk) * 32));
      bf16x8 a2 = __builtin_bit_cast(
          bf16x8, *(const short8v*)(abase + ((2 * SNUM + sub) * 27 + kk) * 32));
      int dz = kk / 9, dy = (kk / 3) % 3, dx = kk % 3;
      __builtin_amdgcn_s_setprio(1);
#pragma unroll
      for (int rc = 0; rc < 4; ++rc) {
        int line = ((rc >> 1) + dz) * 4 + (rc & 1) + dy;
        int xl = n + dx;
        if (xl > XLOC - 1) xl = XLOC - 1;
        int byte = (line * XLOC + xl) * 64 + ((g ^ ((xl >> 1) & 3)) << 4);
        bf16x8 bh = __builtin_bit_cast(bf16x8, *(const short8v*)((const char*)Thi + byte));
        bf16x8 bl = __builtin_bit_cast(bf16x8, *(const short8v*)((const char*)Tlo + byte));
        acc[rc][0] = __builtin_amdgcn_mfma_f32_16x16x32_bf16(a0, bh, acc[rc][0], 0, 0, 0);
        acc[rc][0] = __builtin_amdgcn_mfma_f32_16x16x32_bf16(a2, bh, acc[rc][0], 0, 0, 0);
        acc[rc][0] = __builtin_amdgcn_mfma_f32_16x16x32_bf16(a0, bl, acc[rc][0], 0, 0, 0);
      }
      __builtin_amdgcn_s_setprio(0);
    }
  }
#pragma unroll
  for (int r = 0; r < 4; ++r) {
    float v = fmaxf(fmaxf(acc[0][0][r], acc[1][0][r]),
                    fmaxf(acc[2][0][r], acc[3][0][r]));
    float v2 = fmaxf(v, __shfl_xor(v, 1));
    int o = wave * 16 + 4 * g + r;
    int pxl = n >> 1;
    if (!(n & 1) && pxl < DPL) {
      int px = xh * DPL + pxl;
      float rv = fmaxf(v2 + bias[o], 0.f);
      out[((((size_t)b * COUT + o) * DP + pz) * DP + py) * DP + px] = rv;
    }
  }
}

// ---------------------------------------------------------------------------
// conv4, K-split + N-repacked (round-9 proven).
__global__ __launch_bounds__(512) void k_conv4ks(
    const u16* __restrict__ Apack, const float* __restrict__ in,
    float* __restrict__ P) {
  __shared__ __align__(16) u16 T[343 * 32];
  const int tid = threadIdx.x;
  const int wave = tid >> 6, lane = tid & 63;
  const int n = lane & 15, g = lane >> 4;
  const int q = blockIdx.x;
  const int third = q >> 3;
  const int r8 = q & 7;
  const int ph = r8 >> 2, sub = r8 & 3;
  const int b = blockIdx.y;

  for (int i = tid; i < 343 * 16; i += 512) {
    int jp = i & 15, pos = i >> 4;
    int c = sub * 32 + 2 * jp;
    const float* src = in + (size_t)(b * 128 + c) * 343 + pos;
    float v0 = src[0];
    float v1 = src[343];
    u16 h0 = f2bf(v0), h1 = f2bf(v1);
    u16 a0 = ph ? f2bf(v0 - bf2f(h0)) : h0;
    u16 a1 = ph ? f2bf(v1 - bf2f(h1)) : h1;
    int byte = pos * 64 + (((jp >> 2) ^ (pos & 3)) << 4) + ((jp & 3) << 2);
    *(u32*)((char*)T + byte) = (u32)a0 | ((u32)a1 << 16);
  }
  __syncthreads();

  f32x4 acc[2][4] = {};
  const int ys = n >> 2, xo = n & 3;
  for (int t = 0; t < 9; ++t) {
    int kk = third * 9 + t;
    int dz = kk / 9, dy = (kk / 3) % 3, dx = kk % 3;
    bf16x8 a0[2], a2[2];
#pragma unroll
    for (int mr = 0; mr < 2; ++mr) {
      int mtile = wave + 8 * mr;
      const u16* base = Apack + (size_t)(mtile * 16 + n) * 10368 + 8 * g;
      if (ph == 0) {
        a0[mr] = __builtin_bit_cast(
            bf16x8, *(const short8v*)(base + ((0 * 4 + sub) * 27 + kk) * 32));
        a2[mr] = __builtin_bit_cast(
            bf16x8, *(const short8v*)(base + ((2 * 4 + sub) * 27 + kk) * 32));
      } else {
        a0[mr] = __builtin_bit_cast(
            bf16x8, *(const short8v*)(base + ((1 * 4 + sub) * 27 + kk) * 32));
      }
    }
    int ybase = (ys + dy) * 7 + xo + dx;
#pragma unroll
    for (int zr = 0; zr < 4; ++zr) {
      int pos = (zr + dz) * 49 + ybase;
      int byte = pos * 64 + ((g ^ (pos & 3)) << 4);
      bf16x8 bfr = __builtin_bit_cast(bf16x8, *(const short8v*)((const char*)T + byte));
#pragma unroll
      for (int mr = 0; mr < 2; ++mr) {
        acc[mr][zr] = __builtin_amdgcn_mfma_f32_16x16x32_bf16(a0[mr], bfr, acc[mr][zr], 0, 0, 0);
        if (ph == 0)
          acc[mr][zr] = __builtin_amdgcn_mfma_f32_16x16x32_bf16(a2[mr], bfr, acc[mr][zr], 0, 0, 0);
      }
    }
  }
  float* Pq = P + (size_t)(q * 8 + b) * 16384;
#pragma unroll
  for (int mr = 0; mr < 2; ++mr) {
    int mtile = wave + 8 * mr;
#pragma unroll
    for (int zr = 0; zr < 4; ++zr) {
#pragma unroll
      for (int r = 0; r < 4; ++r) {
        int o = mtile * 16 + 4 * g + r;
        Pq[o * 64 + zr * 16 + n] = acc[mr][zr][r];
      }
    }
  }
}

__global__ __launch_bounds__(256) void k_fin4(const float* __restrict__ P,
                                              const float* __restrict__ bias,
                                              float* __restrict__ h4) {
  int t = blockIdx.x * 256 + threadIdx.x;
  if (t >= 16384) return;
  int w = t & 7;
  int o = (t >> 3) & 255;
  int b = t >> 11;
  int pd = w >> 2, p2 = (w >> 1) & 1, pw = w & 1;
  float m = -1e30f;
#pragma unroll
  for (int dz = 0; dz < 2; ++dz)
#pragma unroll
    for (int dy = 0; dy < 2; ++dy)
#pragma unroll
      for (int dx = 0; dx < 2; ++dx) {
        int pos = (2 * pd + dz) * 16 + (2 * p2 + dy) * 4 + (2 * pw + dx);
        float s = 0.f;
        for (int q = 0; q < 24; ++q)
          s += P[(size_t)(q * 8 + b) * 16384 + o * 64 + pos];
        m = fmaxf(m, s);
      }
  h4[(size_t)b * 2048 + o * 8 + w] = fmaxf(m + bias[o], 0.f);
}

// ---------------------------------------------------------------------------
// fc1 (round-15): K split 4 ways across waves, LDS cross-wave reduce.
__global__ __launch_bounds__(256) void k_fc1(const float* __restrict__ v,
                                             const float* __restrict__ W,
                                             const float* __restrict__ bias,
                                             float* __restrict__ y) {
  int o = blockIdx.x;
  int tid = threadIdx.x;
  int wave = tid >> 6, lane = tid & 63;
  __shared__ float red[4][8];
  float acc[8] = {};
  const float* wp = W + (size_t)o * 2048 + wave * 512;
  const float* vp = v + wave * 512;
  for (int k = lane; k < 512; k += 64) {
    float wv = wp[k];
#pragma unroll
    for (int bb = 0; bb < 8; ++bb)
      acc[bb] = fmaf(vp[bb * 2048 + k], wv, acc[bb]);
  }
#pragma unroll
  for (int off = 32; off; off >>= 1)
#pragma unroll
    for (int bb = 0; bb < 8; ++bb) acc[bb] += __shfl_xor(acc[bb], off);
  if (lane == 0) {
#pragma unroll
    for (int bb = 0; bb < 8; ++bb) red[wave][bb] = acc[bb];
  }
  __syncthreads();
  if (tid < 8) {
    float s = red[0][tid] + red[1][tid] + red[2][tid] + red[3][tid];
    y[tid * 1024 + o] = fmaxf(s + bias[o], 0.f);
  }
}

__global__ __launch_bounds__(64) void k_fc2(const float* __restrict__ v,
                                            const float* __restrict__ W,
                                            const float* __restrict__ bias,
                                            float* __restrict__ y) {
  int o = blockIdx.x;
  int lane = threadIdx.x;
  float acc[8] = {};
  for (int k = lane; k < 1024; k += 64) {
    float wv = W[o * 1024 + k];
#pragma unroll
    for (int bb = 0; bb < 8; ++bb)
      acc[bb] = fmaf(v[bb * 1024 + k], wv, acc[bb]);
  }
#pragma unroll
  for (int off = 32; off; off >>= 1)
#pragma unroll
    for (int bb = 0; bb < 8; ++bb) acc[bb] += __shfl_xor(acc[bb], off);
  if (lane == 0) {
    float bo = bias[o];
#pragma unroll
    for (int bb = 0; bb < 8; ++bb) y[bb * 29 + o] = acc[bb] + bo;
  }
}

// ---------------------------------------------------------------------------
extern "C" void kernel_launch(void* const* d_in, const int* in_sizes, int n_in,
                              void* d_out, int out_size, void* d_ws, size_t ws_size,
                              hipStream_t stream) {
  const float* x   = (const float*)d_in[0];
  const float* sig = (const float*)d_in[1];
  const float* w1  = (const float*)d_in[2];
  const float* b1  = (const float*)d_in[3];
  const float* w2  = (const float*)d_in[4];
  const float* b2  = (const float*)d_in[5];
  const float* w3  = (const float*)d_in[6];
  const float* b3  = (const float*)d_in[7];
  const float* w4  = (const float*)d_in[8];
  const float* b4  = (const float*)d_in[9];
  const float* fw1 = (const float*)d_in[10];
  const float* fb1 = (const float*)d_in[11];
  const float* fw2 = (const float*)d_in[12];
  const float* fb2 = (const float*)d_in[13];

  char* ws = (char*)d_ws;
  // Deterministic runtime layout choice (same ws_size every call):
  // BIG (>=114MB): single 8-batch pass. cube8 @0 (65,856,000), h1 @65,856,000
  //   (40,247,296 -> 106,103,296); packs above: ah1 @106,200,000, al1
  //   @106,250,000, ap2 @106,300,000, ap3 @106,700,000, ap4 @108,100,000
  //   (-> 113,408,416); cnt @113,500,000, lists @113,501,024 (-> 113.6MB).
  //   After conv1 cube dead: h2 @0, h3 @8,400,000, P @10,000,000 (->22.58M),
  //   h4 @22,600,000, y1 @22,700,000.
  // SMALL: round-19 proven half-split layout (peak 90.8MB).
  const bool big = ws_size >= (size_t)114000000;

  u32*   cube; float* h1; u16 *ah1, *al1, *ap2, *ap3, *ap4;
  float *h2, *h3, *P, *h4, *y1; int *cnt, *lists;
  if (big) {
    cube  = (u32*)(ws + 0);
    h1    = (float*)(ws + 65856000);
    ah1   = (u16*)(ws + 106200000);
    al1   = (u16*)(ws + 106250000);
    ap2   = (u16*)(ws + 106300000);
    ap3   = (u16*)(ws + 106700000);
    ap4   = (u16*)(ws + 108100000);
    cnt   = (int*)(ws + 113500000);
    lists = (int*)(ws + 113501024);
    h2    = (float*)(ws + 0);
    h3    = (float*)(ws + 8400000);
    P     = (float*)(ws + 10000000);
    h4    = (float*)(ws + 22600000);
    y1    = (float*)(ws + 22700000);
  } else {
    cube  = (u32*)(ws + 0);
    P     = (float*)(ws + 0);
    h1    = (float*)(ws + 32928000);
    ah1   = (u16*)(ws + 73200000);
    al1   = (u16*)(ws + 73250000);
    ap2   = (u16*)(ws + 73300000);
    ap3   = (u16*)(ws + 73700000);
    ap4   = (u16*)(ws + 75100000);
    h2    = (float*)(ws + 80500000);
    h3    = (float*)(ws + 89000000);
    h4    = (float*)(ws + 90500000);
    y1    = (float*)(ws + 90600000);
    cnt   = (int*)(ws + 90700000);
    lists = (int*)(ws + 90701024);
  }

  const int PACK_TOTAL = 48 + 32 * 224 + 64 * 2592 + 128 * 5184 + 256 * 10368;
  k_packall<<<(PACK_TOTAL + 255) / 256, 256, 0, stream>>>(
      w1, ah1, al1, w2, ap2, w3, ap3, w4, ap4, cnt);

  const int N4 = (BATCH * NEL * DIMV * DIMV * DIMV) / 4;
  k_scan<<<(N4 + 255) / 256, 256, 0, stream>>>(x, cnt, lists);

  if (big) {
    k_gather<<<dim3(DIMV, 8 * NEL), 256, 0, stream>>>(cnt, lists, sig, cube, 0);
    k_conv1<<<dim3(34 * 34, 8), 256, 0, stream>>>(ah1, al1, cube, b1, h1, 0);
  } else {
    for (int half = 0; half < 2; ++half) {
      int b0 = 4 * half;
      k_gather<<<dim3(DIMV, 4 * NEL), 256, 0, stream>>>(cnt, lists, sig, cube, b0);
      k_conv1<<<dim3(34 * 34, 4), 256, 0, stream>>>(ah1, al1, cube, b1, h1, b0);
    }
  }

  //          CINL COUT DIN  W  XS
  k_conv_m<32,  64, 34, 4, 2><<<dim3(16 * 16 * 2, 8), 256, 0, stream>>>(ap2, h1, b2, h2);
  k_conv_m<64, 128, 16, 8, 1><<<dim3(7 * 7, 8),       512, 0, stream>>>(ap3, h2, b3, h3);

  k_conv4ks<<<dim3(24, 8), 512, 0, stream>>>(ap4, h3, P);
  k_fin4<<<64, 256, 0, stream>>>(P, b4, h4);

  k_fc1<<<1024, 256, 0, stream>>>(h4, fw1, fb1, y1);
  k_fc2<<<29, 64, 0, stream>>>(y1, fw2, fb2, (float*)d_out);
}